// Round 8
// baseline (206.048 us; speedup 1.0000x reference)
//
#include <hip/hip_runtime.h>
#include <math.h>

#define D 64
#define K 512
#define ROWS 131072       // 32*64*64
#define NELEM (ROWS * D)  // 8388608
#define TGAP 64.0f        // flag threshold in 2^20-scaled units (= 6.1e-5 unscaled)
#define FLAGBIT (1 << 30)
#define RPB 128           // rows per block: 4 waves x 32 rows
#define NBLK (ROWS / RPB) // 1024 blocks -> 4 blocks/CU, 16 waves/CU

typedef _Float16 half8 __attribute__((ext_vector_type(8)));
typedef float floatx4 __attribute__((ext_vector_type(4)));

// ws layout (bytes):
//   [0,8)            double loss accumulator
//   [8,12)           uint32 ticket counter (fused finalize)
//   [4096,6144)      float  Bn20[512]    column norms * 2^20 (numpy order, exact scale)
//   [8192,73728)     _Float16 gH[32768]  hi B-fragments, MFMA fragment order
//   [73728,139264)   _Float16 gL[32768]  lo B-fragments

// ---------------------------------------------------------------------------
// Setup: codebook -> scaled fp16 hi/lo in B-fragment order (global), + norms,
// + zero loss accumulator and ticket.
// frag layout: half index = (((n>>4)*2 + (k>>5))*64 + ((k>>3)&3)*16 + (n&15))*8 + (k&7)
// ---------------------------------------------------------------------------
__global__ __launch_bounds__(512) void vq_setup(const float* __restrict__ cb,
                                                _Float16* __restrict__ gH,
                                                _Float16* __restrict__ gL,
                                                float* __restrict__ Bn,
                                                unsigned long long* __restrict__ zws) {
    int idx = blockIdx.x * 512 + threadIdx.x;   // 64 blocks x 512 = 32768
    int k = idx >> 9, n = idx & 511;
    float c = cb[idx];
    float t = c * 4096.0f;                      // 2^12, exact
    _Float16 ch = (_Float16)t;
    float r = t - (float)ch;                    // exact
    _Float16 cl = (_Float16)(r * 4096.0f);      // scale 2^24
    int off = (((n >> 4) * 2 + (k >> 5)) * 64 + ((k >> 3) & 3) * 16 + (n & 15)) * 8 + (k & 7);
    gH[off] = ch;
    gL[off] = cl;
    if (blockIdx.x == 1 && threadIdx.x < 4) zws[threadIdx.x] = 0ull;  // loss + ticket
    if (blockIdx.x == 0) {
#pragma clang fp contract(off)
        int j = threadIdx.x;
        float b = 0.f;
        for (int kk = 0; kk < D; ++kk) { float cc = cb[kk * K + j]; b = b + cc * cc; }
        Bn[j] = b * 0x1p20f;                    // exact power-of-2 scale
    }
}

// ---------------------------------------------------------------------------
// Main: MFMA filter, 256 thr = 4 waves, 32 rows/wave (2 tiles of 16).
// R7 hot-loop structure (proven 67us, VGPR 52, spill-free) with:
//  (1) pair-staging: 2 tiles per __syncthreads (16 barriers instead of 32),
//      doubling the prefetch window and halving the vmcnt(0)+barrier drains
//      that paced R7 (occupancy rose 60%, dur flat => barrier-bound).
//  (2) fused exact rescan + ticket finalize (R1/R4-proven tail) — removes
//      2 kernel launches + bitmap/lpart global round-trips (~35us of
//      non-main wall time measured R4-vs-R7). Live set ~50 regs leaves
//      headroom for the cold-path rescan without the 64-VGPR squeeze that
//      sank R1/R4 (their A-frags alone were 64 regs).
// ---------------------------------------------------------------------------
__global__ __launch_bounds__(256, 2) void vq_main(const float* __restrict__ x,
                                                  const float* __restrict__ cb,
                                                  const _Float16* __restrict__ gH,
                                                  const _Float16* __restrict__ gL,
                                                  const float* __restrict__ Bn,
                                                  float* __restrict__ out,
                                                  double* __restrict__ loss_acc,
                                                  unsigned int* __restrict__ ticket) {
    __shared__ float ldsB[K];
    __shared__ half8 bstage[2][2][4][64];  // [buf][pair-half][part][lane], 16 KB
    __shared__ int rowinfo[4][32];
    __shared__ unsigned int flagbits[4];
    __shared__ float wavesum[4];

    const int tid = threadIdx.x;
    const int lane = tid & 63;
    const int w = tid >> 6;
    const int quad = lane >> 4;
    const int nn = lane & 15;

    ldsB[tid] = Bn[tid];
    ldsB[tid + 256] = Bn[tid + 256];
    if (tid < 4) flagbits[tid] = 0;

    const int rowBase = blockIdx.x * RPB + w * 32;

    // A-fragments: lane holds A[m=nn][k=quad*8+j] per k-half s, scaled hi/lo
    half8 xh[2][2], xl[2][2];
    #pragma unroll
    for (int tt = 0; tt < 2; ++tt) {
        #pragma unroll
        for (int s = 0; s < 2; ++s) {
            const float* xp = x + (size_t)(rowBase + tt * 16 + nn) * D + s * 32 + quad * 8;
            float4 v0 = *(const float4*)xp;
            float4 v1 = *(const float4*)(xp + 4);
            float vv[8] = {v0.x, v0.y, v0.z, v0.w, v1.x, v1.y, v1.z, v1.w};
            #pragma unroll
            for (int j = 0; j < 8; ++j) {
                float t = vv[j] * 256.0f;        // 2^8, exact
                _Float16 h = (_Float16)t;
                float r = t - (float)h;          // exact
                xh[tt][s][j] = h;
                xl[tt][s][j] = (_Float16)(r * 4096.0f);  // scale 2^20
            }
        }
    }

    // wave w stages part w of tile t_: {w&1 ? gL : gH}, chunk t_*2 + (w>>1).
    // LDS dest is wave-uniform base; HW writes lane l at base + l*16 (linear).
#define STAGE(buf, t_) do {                                                         \
        const _Float16* gsrc = ((w & 1) ? gL : gH)                                  \
                             + ((((t_) * 2 + (w >> 1)) * 64 + lane) * 8);           \
        __builtin_amdgcn_global_load_lds(                                           \
            (const __attribute__((address_space(1))) void*)gsrc,                    \
            (__attribute__((address_space(3))) void*)&bstage[buf][(t_) & 1][w][0],  \
            16, 0, 0);                                                              \
    } while (0)

    STAGE(0, 0);
    STAGE(0, 1);
    __syncthreads();   // covers ldsB writes + prologue stage (vmcnt drain)

    float m1[2][4], m2[2][4];
    int   i1[2][4];
    #pragma unroll
    for (int tt = 0; tt < 2; ++tt)
        #pragma unroll
        for (int r = 0; r < 4; ++r) { m1[tt][r] = INFINITY; m2[tt][r] = INFINITY; i1[tt][r] = 0; }

    for (int p = 0; p < 16; ++p) {                  // 16 tile-pairs, 1 barrier each
        const int cur = p & 1;
        if (p < 15) { STAGE(cur ^ 1, 2 * p + 2); STAGE(cur ^ 1, 2 * p + 3); }
        #pragma unroll
        for (int h = 0; h < 2; ++h) {
            const int t = 2 * p + h;
            half8 bh0 = bstage[cur][h][0][lane];    // ds_read_b128, conflict-free
            half8 bl0 = bstage[cur][h][1][lane];
            half8 bh1 = bstage[cur][h][2][lane];
            half8 bl1 = bstage[cur][h][3][lane];
            int col = t * 16 + nn;
            float Bj = ldsB[col];                   // B*2^20
            #pragma unroll
            for (int tt = 0; tt < 2; ++tt) {
                floatx4 a1 = {0.f, 0.f, 0.f, 0.f};
                floatx4 a2 = {0.f, 0.f, 0.f, 0.f};
                a2 = __builtin_amdgcn_mfma_f32_16x16x32_f16(xl[tt][0], bh0, a2, 0, 0, 0);
                a2 = __builtin_amdgcn_mfma_f32_16x16x32_f16(xh[tt][0], bl0, a2, 0, 0, 0);
                a1 = __builtin_amdgcn_mfma_f32_16x16x32_f16(xh[tt][0], bh0, a1, 0, 0, 0);
                a2 = __builtin_amdgcn_mfma_f32_16x16x32_f16(xl[tt][1], bh1, a2, 0, 0, 0);
                a2 = __builtin_amdgcn_mfma_f32_16x16x32_f16(xh[tt][1], bl1, a2, 0, 0, 0);
                a1 = __builtin_amdgcn_mfma_f32_16x16x32_f16(xh[tt][1], bh1, a1, 0, 0, 0);
                #pragma unroll
                for (int r = 0; r < 4; ++r) {
                    float macc = fmaf(0x1p-12f, a2[r], a1[r]);   // M * 2^20
                    float g = fmaf(-2.0f, macc, Bj);             // (B - 2M) * 2^20
                    float old1 = m1[tt][r];
                    // new 2nd-best of {old1, old2, g} = median of the three
                    m2[tt][r] = __builtin_amdgcn_fmed3f(g, old1, m2[tt][r]);
                    bool c1 = g < old1;
                    m1[tt][r] = c1 ? g : old1;
                    i1[tt][r] = c1 ? col : i1[tt][r];            // strict <, j ascending
                }
            }
        }
        __syncthreads();   // vmcnt(0)+barrier: next pair landed, this buf free
    }
#undef STAGE

    // merge best-2 across the 16 col-lanes (butterfly over low 4 lane bits)
    #pragma unroll
    for (int dlt = 1; dlt < 16; dlt <<= 1) {
        #pragma unroll
        for (int tt = 0; tt < 2; ++tt)
            #pragma unroll
            for (int r = 0; r < 4; ++r) {
                float om1 = __shfl_xor(m1[tt][r], dlt);
                int   oi1 = __shfl_xor(i1[tt][r], dlt);
                float om2 = __shfl_xor(m2[tt][r], dlt);
                bool ofirst = (om1 < m1[tt][r]) || (om1 == m1[tt][r] && oi1 < i1[tt][r]);
                float l1   = ofirst ? m1[tt][r] : om1;
                float cand = ofirst ? om2 : m2[tt][r];
                m1[tt][r] = ofirst ? om1 : m1[tt][r];
                i1[tt][r] = ofirst ? oi1 : i1[tt][r];
                m2[tt][r] = fminf(cand, l1);
            }
    }

    // record results; flagged rows -> per-wave LDS bitmap word
    if (nn == 0) {
        #pragma unroll
        for (int tt = 0; tt < 2; ++tt)
            #pragma unroll
            for (int r = 0; r < 4; ++r) {
                int rl = tt * 16 + quad * 4 + r;
                bool flg = (m2[tt][r] - m1[tt][r]) < TGAP;
                rowinfo[w][rl] = i1[tt][r] | (flg ? FLAGBIT : 0);
                if (flg) atomicOr(&flagbits[w], 1u << rl);
            }
    }
    __syncthreads();

    // coalesced output + loss for certain rows
    float lsum = 0.f;
    #pragma unroll
    for (int tt = 0; tt < 2; ++tt) {
        #pragma unroll
        for (int p = 0; p < 4; ++p) {
            int rl = tt * 16 + p * 4 + quad;
            int info = rowinfo[w][rl];
            if (!(info & FLAGBIT)) {
                int j = info & 511;
                int kb = nn * 4;
                float q0 = cb[(kb + 0) * K + j];
                float q1 = cb[(kb + 1) * K + j];
                float q2 = cb[(kb + 2) * K + j];
                float q3 = cb[(kb + 3) * K + j];
                size_t row = (size_t)rowBase + rl;
                float4 xv = *(const float4*)(x + row * D + kb);
                float e0 = q0 - xv.x, e1 = q1 - xv.y, e2 = q2 - xv.z, e3 = q3 - xv.w;
                lsum += e0 * e0 + e1 * e1 + e2 * e2 + e3 * e3;
                *(float4*)(out + row * D + kb) = make_float4(q0, q1, q2, q3);
            }
        }
    }

    // fused exact rescan: this wave handles its own 32-row flag word.
    // Exact numpy-order pipeline; lane handles 8 columns (j = lane + 64m).
    unsigned int fmask = flagbits[w];
    if (fmask) {
#pragma clang fp contract(off)
        float bn[8];
        #pragma unroll
        for (int m = 0; m < 8; ++m) bn[m] = 0.f;
        for (int k = 0; k < D; ++k) {
            const float* crow = cb + k * K + lane;
            #pragma unroll
            for (int m = 0; m < 8; ++m) {
                float c = crow[m * 64];
                bn[m] = bn[m] + c * c;
            }
        }
        while (fmask) {
            int b = __builtin_ctz(fmask);
            fmask &= fmask - 1;
            int row = rowBase + b;
            const float* xr = x + (size_t)row * D;
            // A = np.sum(x**2, axis=1): pairwise n=64 emulation
            float A0;
            {
                float rr[8];
                #pragma unroll
                for (int l = 0; l < 8; ++l) rr[l] = xr[l] * xr[l];
                #pragma unroll
                for (int m = 1; m < 8; ++m)
                    #pragma unroll
                    for (int l = 0; l < 8; ++l) {
                        float q = xr[8 * m + l] * xr[8 * m + l];
                        rr[l] = rr[l] + q;
                    }
                A0 = ((rr[0] + rr[1]) + (rr[2] + rr[3])) + ((rr[4] + rr[5]) + (rr[6] + rr[7]));
            }
            float a[8];
            #pragma unroll
            for (int m = 0; m < 8; ++m) a[m] = 0.f;
            for (int k = 0; k < D; ++k) {
                float xk = xr[k];
                const float* crow = cb + k * K + lane;
                #pragma unroll
                for (int m = 0; m < 8; ++m)
                    a[m] = fmaf(xk, crow[m * 64], a[m]);   // sequential-k fma chain
            }
            float db = INFINITY; int jb = 0x7fffffff;
            #pragma unroll
            for (int m = 0; m < 8; ++m) {
                float s = A0 + bn[m];
                float t2 = 2.0f * a[m];
                float d = s - t2;                  // fl(fl(A+B) - fl(2M))
                int j = lane + (m << 6);
                if (d < db) { db = d; jb = j; }
            }
            for (int s = 1; s < 64; s <<= 1) {     // first-index global argmin
                float od = __shfl_xor(db, s);
                int oj = __shfl_xor(jb, s);
                if ((od < db) || (od == db && oj < jb)) { db = od; jb = oj; }
            }
            float q = cb[lane * K + jb];
            out[(size_t)row * D + lane] = q;
            float e = q - xr[lane];
            lsum += e * e;
        }
    }

    #pragma unroll
    for (int off = 32; off > 0; off >>= 1) lsum += __shfl_down(lsum, off);
    if (lane == 0) wavesum[w] = lsum;
    __syncthreads();
    if (tid == 0) {
        double tot = (double)wavesum[0] + (double)wavesum[1]
                   + (double)wavesum[2] + (double)wavesum[3];
        atomicAdd(loss_acc, tot);
        __threadfence();
        unsigned int my = atomicAdd(ticket, 1u);
        if (my == (unsigned int)(gridDim.x - 1)) {
            // last block: all prior loss adds are ordered before their tickets
            double total = atomicAdd(loss_acc, 0.0);
            out[NELEM] = (float)(total * (1.25 / (double)NELEM));  // (1+beta)*mean
        }
    }
}

extern "C" void kernel_launch(void* const* d_in, const int* in_sizes, int n_in,
                              void* d_out, int out_size, void* d_ws, size_t ws_size,
                              hipStream_t stream) {
    const float* x  = (const float*)d_in[0];   // [32,64,64,64] fp32
    const float* cb = (const float*)d_in[1];   // [64,512] fp32
    float* out = (float*)d_out;                // [8388608] out + [1] loss
    double* loss_acc     = (double*)d_ws;
    unsigned int* ticket = (unsigned int*)((char*)d_ws + 8);
    float* Bn        = (float*)((char*)d_ws + 4096);
    _Float16* gH     = (_Float16*)((char*)d_ws + 8192);
    _Float16* gL     = (_Float16*)((char*)d_ws + 73728);

    vq_setup<<<64, 512, 0, stream>>>(cb, gH, gL, Bn, (unsigned long long*)d_ws);
    vq_main<<<NBLK, 256, 0, stream>>>(x, cb, gH, gL, Bn, out, loss_acc, ticket);
}